// Round 10
// baseline (215.771 us; speedup 1.0000x reference)
//
#include <hip/hip_runtime.h>

#define NN 100000
#define NE 3200000
#define HC 16

#define DSUP_BITS 11
#define DSUP 2048                 // dst-super size (acc table)
#define NSUP 49                   // ceil(NN/2048)
#define SSL_BITS 12
#define SSL 4096                  // src-slice size (LDS-staged table)
#define NSL 25                    // ceil(NN/4096)
#define NT (NSUP*NSL)             // 1225 tiles
#define NT1 (NT+1)
#define CHUNK_S 4096
#define NCH 782                   // ceil(NE/CHUNK_S)
#define NCCP 784                  // padded TH row stride
#define MCAP 3584                 // merge stage capacity (tile max ~2950)
#define NPAIR 13                  // slice-pairs per super
#define NBLK1 (NSUP*NPAIR)        // 637 tile-pass blocks

typedef unsigned uv4 __attribute__((ext_vector_type(4)));
typedef int      iv4 __attribute__((ext_vector_type(4)));

// ---------- pass 1: per-chunk counting sort by tile key ----------

__global__ __launch_bounds__(256) void k_sortchunk(const int* __restrict__ src,
                                                   const int* __restrict__ dst,
                                                   unsigned short* __restrict__ Hoff,
                                                   unsigned* __restrict__ binned) {
    __shared__ unsigned h[NT1];
    __shared__ unsigned sorted[CHUNK_S];
    __shared__ unsigned wsum[4];
    int tid = threadIdx.x;
    int c = blockIdx.x;
    int b0 = c * CHUNK_S;
    int e1 = min(b0 + CHUNK_S, NE);
    int cnt = e1 - b0;                    // always multiple of 4

    for (int j = tid; j < NT1; j += 256) h[j] = 0;
    __syncthreads();

    for (int v = b0 + tid * 4; v + 3 < e1; v += 1024) {
        iv4 d4 = *(const iv4*)(dst + v);
        iv4 s4 = *(const iv4*)(src + v);
        atomicAdd(&h[((unsigned)d4.x >> DSUP_BITS) * NSL + ((unsigned)s4.x >> SSL_BITS)], 1u);
        atomicAdd(&h[((unsigned)d4.y >> DSUP_BITS) * NSL + ((unsigned)s4.y >> SSL_BITS)], 1u);
        atomicAdd(&h[((unsigned)d4.z >> DSUP_BITS) * NSL + ((unsigned)s4.z >> SSL_BITS)], 1u);
        atomicAdd(&h[((unsigned)d4.w >> DSUP_BITS) * NSL + ((unsigned)s4.w >> SSL_BITS)], 1u);
    }
    __syncthreads();

    // block exclusive scan of h[0..NT1), 5 cells/thread (1280 >= 1226)
    int i0 = tid * 5;
    unsigned v0 = (i0 + 0 < NT1) ? h[i0 + 0] : 0;
    unsigned v1 = (i0 + 1 < NT1) ? h[i0 + 1] : 0;
    unsigned v2 = (i0 + 2 < NT1) ? h[i0 + 2] : 0;
    unsigned v3 = (i0 + 3 < NT1) ? h[i0 + 3] : 0;
    unsigned v4 = (i0 + 4 < NT1) ? h[i0 + 4] : 0;
    unsigned lsum = v0 + v1 + v2 + v3 + v4;
    unsigned sc = lsum;
#pragma unroll
    for (int off = 1; off < 64; off <<= 1) {
        unsigned u = __shfl_up(sc, off, 64);
        if ((tid & 63) >= off) sc += u;
    }
    int wave = tid >> 6;
    if ((tid & 63) == 63) wsum[wave] = sc;
    __syncthreads();
    unsigned wpre = 0;
    for (int w = 0; w < wave; ++w) wpre += wsum[w];
    unsigned excl = wpre + sc - lsum;
    __syncthreads();
    unsigned short* row = Hoff + (size_t)c * NT1;
    unsigned run = excl;
    if (i0 + 0 < NT1) { h[i0 + 0] = run; row[i0 + 0] = (unsigned short)run; run += v0; }
    if (i0 + 1 < NT1) { h[i0 + 1] = run; row[i0 + 1] = (unsigned short)run; run += v1; }
    if (i0 + 2 < NT1) { h[i0 + 2] = run; row[i0 + 2] = (unsigned short)run; run += v2; }
    if (i0 + 3 < NT1) { h[i0 + 3] = run; row[i0 + 3] = (unsigned short)run; run += v3; }
    if (i0 + 4 < NT1) { h[i0 + 4] = run; row[i0 + 4] = (unsigned short)run; }
    __syncthreads();

    for (int v = b0 + tid * 4; v + 3 < e1; v += 1024) {
        iv4 d4 = *(const iv4*)(dst + v);
        iv4 s4 = *(const iv4*)(src + v);
        {   unsigned d = (unsigned)d4.x, s = (unsigned)s4.x;
            unsigned pos = atomicAdd(&h[(d >> DSUP_BITS) * NSL + (s >> SSL_BITS)], 1u);
            sorted[pos] = ((s & (SSL - 1)) << DSUP_BITS) | (d & (DSUP - 1)); }
        {   unsigned d = (unsigned)d4.y, s = (unsigned)s4.y;
            unsigned pos = atomicAdd(&h[(d >> DSUP_BITS) * NSL + (s >> SSL_BITS)], 1u);
            sorted[pos] = ((s & (SSL - 1)) << DSUP_BITS) | (d & (DSUP - 1)); }
        {   unsigned d = (unsigned)d4.z, s = (unsigned)s4.z;
            unsigned pos = atomicAdd(&h[(d >> DSUP_BITS) * NSL + (s >> SSL_BITS)], 1u);
            sorted[pos] = ((s & (SSL - 1)) << DSUP_BITS) | (d & (DSUP - 1)); }
        {   unsigned d = (unsigned)d4.w, s = (unsigned)s4.w;
            unsigned pos = atomicAdd(&h[(d >> DSUP_BITS) * NSL + (s >> SSL_BITS)], 1u);
            sorted[pos] = ((s & (SSL - 1)) << DSUP_BITS) | (d & (DSUP - 1)); }
    }
    __syncthreads();

    unsigned* out = binned + (size_t)c * CHUNK_S;
    for (int j = tid * 4; j + 3 < cnt; j += 1024)
        *(uv4*)(out + j) = *(const uv4*)(sorted + j);
}

// ---------- pass 2: transpose Hoff[chunk][tile] -> TH[tile][chunk] ----------

__global__ __launch_bounds__(256) void k_transT(const unsigned short* __restrict__ Hoff,
                                                unsigned short* __restrict__ TH) {
    __shared__ unsigned short tile[32][33];
    int tx = threadIdx.x & 31;
    int ty0 = (threadIdx.x >> 5) * 4;
    int c0 = blockIdx.x * 32;
    int b0 = blockIdx.y * 32;
#pragma unroll
    for (int k = 0; k < 4; ++k) {
        int c = c0 + ty0 + k, b = b0 + tx;
        tile[ty0 + k][tx] = (c < NCH && b < NT1) ? Hoff[(size_t)c * NT1 + b] : (unsigned short)0;
    }
    __syncthreads();
#pragma unroll
    for (int k = 0; k < 4; ++k) {
        int b = b0 + ty0 + k, c = c0 + tx;
        if (b < NT1 && c < NCH) TH[(size_t)b * NCCP + c] = tile[tx][ty0 + k];
    }
}

// ---------- pass 3: per-tile totals + global base scan ----------

__global__ __launch_bounds__(64) void k_totals(const unsigned short* __restrict__ TH,
                                               unsigned* __restrict__ totals) {
    int b = blockIdx.x;
    int lane = threadIdx.x;
    const unsigned short* r0 = TH + (size_t)b * NCCP;
    const unsigned short* r1 = r0 + NCCP;
    unsigned s = 0;
    for (int c = lane; c < NCH; c += 64) s += (unsigned)r1[c] - (unsigned)r0[c];
#pragma unroll
    for (int off = 32; off >= 1; off >>= 1) s += __shfl_xor(s, off, 64);
    if (lane == 0) totals[b] = s;
}

__global__ __launch_bounds__(1024) void k_base3(const unsigned* __restrict__ totals,
                                                unsigned* __restrict__ gbase) {
    __shared__ unsigned s[1024];
    int t = threadIdx.x;
    unsigned v0 = (2 * t     < NT) ? ((totals[2 * t]     + 15u) & ~15u) : 0;
    unsigned v1 = (2 * t + 1 < NT) ? ((totals[2 * t + 1] + 15u) & ~15u) : 0;
    s[t] = v0 + v1;
    __syncthreads();
    for (int off = 1; off < 1024; off <<= 1) {
        unsigned u = (t >= off) ? s[t - off] : 0;
        __syncthreads();
        s[t] += u;
        __syncthreads();
    }
    unsigned excl = s[t] - (v0 + v1);
    if (2 * t     < NT) gbase[2 * t]     = excl;
    if (2 * t + 1 < NT) gbase[2 * t + 1] = excl + v0;
}

// ---------- pass 4: merge per-tile segments -> contiguous runs + per-tile dst counts ----------

__global__ __launch_bounds__(256) void k_merge(const unsigned* __restrict__ binned,
                                               const unsigned short* __restrict__ TH,
                                               const unsigned* __restrict__ gbase,
                                               unsigned* __restrict__ merged,
                                               unsigned short* __restrict__ cntpart) {
    __shared__ unsigned short th0s[NCH];
    __shared__ unsigned short lens[NCH];
    __shared__ unsigned S[NCH + 1];
    __shared__ unsigned wsum[4];
    __shared__ unsigned cnt[DSUP];
    __shared__ unsigned stage[MCAP];
    int tid = threadIdx.x, t = blockIdx.x;

    const unsigned short* r0 = TH + (size_t)t * NCCP;
    const unsigned short* r1 = r0 + NCCP;
    for (int c = tid; c < NCH; c += 256) {
        unsigned a = r0[c];
        th0s[c] = (unsigned short)a;
        lens[c] = (unsigned short)((unsigned)r1[c] - a);
    }
    for (int i = tid; i < DSUP; i += 256) cnt[i] = 0;
    __syncthreads();

    // exclusive scan of lens -> S (4 cells/thread, 1024 >= 783)
    int i0 = tid * 4;
    unsigned v0 = (i0 + 0 < NCH) ? (unsigned)lens[i0 + 0] : 0;
    unsigned v1 = (i0 + 1 < NCH) ? (unsigned)lens[i0 + 1] : 0;
    unsigned v2 = (i0 + 2 < NCH) ? (unsigned)lens[i0 + 2] : 0;
    unsigned v3 = (i0 + 3 < NCH) ? (unsigned)lens[i0 + 3] : 0;
    unsigned lsum = v0 + v1 + v2 + v3;
    unsigned sc = lsum;
#pragma unroll
    for (int off = 1; off < 64; off <<= 1) {
        unsigned u = __shfl_up(sc, off, 64);
        if ((tid & 63) >= off) sc += u;
    }
    int wave = tid >> 6;
    if ((tid & 63) == 63) wsum[wave] = sc;
    __syncthreads();
    unsigned wpre = 0;
    for (int w = 0; w < wave; ++w) wpre += wsum[w];
    unsigned excl = wpre + sc - lsum;
    if (i0 + 0 <= NCH) S[i0 + 0] = excl;
    if (i0 + 1 <= NCH) S[i0 + 1] = excl + v0;
    if (i0 + 2 <= NCH) S[i0 + 2] = excl + v0 + v1;
    if (i0 + 3 <= NCH) S[i0 + 3] = excl + v0 + v1 + v2;
    __syncthreads();

    unsigned T = S[NCH];
    unsigned Tr = (T + 15u) & ~15u;
    unsigned gb = gbase[t];
    if (tid < 16) {                        // zero the <=15 pad slots (guarded away later)
        unsigned q = T + tid;
        if (q < Tr && q < MCAP) stage[q] = 0;
    }

    // gather segments -> LDS stage, count dst_local
    for (int c = tid; c < NCH; c += 256) {
        unsigned off = th0s[c], L = lens[c], base = S[c];
        const unsigned* seg = binned + (size_t)c * CHUNK_S + off;
        for (unsigned j = 0; j < L; ++j) {
            unsigned e = seg[j];
            atomicAdd(&cnt[e & (DSUP - 1)], 1u);
            unsigned pos = base + j;
            if (pos < MCAP) stage[pos] = e;
        }
    }
    __syncthreads();

    unsigned lim = Tr < MCAP ? Tr : (unsigned)MCAP;
    for (unsigned j = tid * 4; j < lim; j += 1024)
        *(uv4*)(merged + gb + j) = *(const uv4*)(stage + j);

    unsigned short* cp = cntpart + (size_t)t * DSUP;
    for (int i = tid; i < DSUP; i += 256) cp[i] = (unsigned short)cnt[i];
}

// ---------- pass 5: combine degree partials -> dinv, p ----------

__global__ __launch_bounds__(256) void k_node1(const unsigned short* __restrict__ cntpart,
                                               const float* __restrict__ x,
                                               float* __restrict__ dinv,
                                               float* __restrict__ p) {
    int n = blockIdx.x * 256 + threadIdx.x;
    if (n >= NN) return;
    int s49 = n >> DSUP_BITS;
    int l = n & (DSUP - 1);
    unsigned deg = 0;
#pragma unroll
    for (int sl = 0; sl < NSL; ++sl)
        deg += (unsigned)cntpart[(size_t)(s49 * NSL + sl) * DSUP + l];
    float di = rsqrtf((float)(deg + 1u));     // +1 self-loop
    dinv[n] = di;
    p[n] = di * x[n];
}

// ---------- pass 6: layer-1 tile aggregation (LDS-resident sources) ----------

__global__ __launch_bounds__(256) void k_l1tile(const unsigned* __restrict__ merged,
                                                const unsigned* __restrict__ gbase,
                                                const unsigned* __restrict__ totals,
                                                const float* __restrict__ p,
                                                float* __restrict__ acc1p) {
    __shared__ float psl[SSL];     // 16 KB
    __shared__ float acc[DSUP];    // 8 KB
    int tid = threadIdx.x, bid = blockIdx.x;
    int s49 = bid / NPAIR, jp = bid % NPAIR;
    for (int i = tid; i < DSUP; i += 256) acc[i] = 0.f;
    for (int half = 0; half < 2; ++half) {
        int sl = jp * 2 + half;
        if (sl >= NSL) break;
        __syncthreads();
        int base = sl << SSL_BITS;
        for (int i = tid; i < SSL; i += 256)
            psl[i] = (base + i < NN) ? p[base + i] : 0.f;
        __syncthreads();
        int k = s49 * NSL + sl;
        unsigned T = totals[k];
        const unsigned* m = merged + gbase[k];
        for (unsigned j = tid * 4; j < T; j += 1024) {
            uv4 e = *(const uv4*)(m + j);
            if (j + 0 < T) atomicAdd(&acc[e.x & (DSUP - 1)], psl[e.x >> DSUP_BITS]);
            if (j + 1 < T) atomicAdd(&acc[e.y & (DSUP - 1)], psl[e.y >> DSUP_BITS]);
            if (j + 2 < T) atomicAdd(&acc[e.z & (DSUP - 1)], psl[e.z >> DSUP_BITS]);
            if (j + 3 < T) atomicAdd(&acc[e.w & (DSUP - 1)], psl[e.w >> DSUP_BITS]);
        }
    }
    __syncthreads();
    float* ap = acc1p + (size_t)bid * DSUP;
    for (int i = tid; i < DSUP; i += 256) ap[i] = acc[i];
}

// ---------- pass 7: combine layer-1 partials + fused MLP -> g ----------

__global__ __launch_bounds__(256) void k_node2(const float* __restrict__ acc1p,
                                               const float* __restrict__ dinv,
                                               const float* __restrict__ p,
                                               const float* __restrict__ W1,
                                               const float* __restrict__ b1,
                                               const float* __restrict__ W2,
                                               float2* __restrict__ g) {
    int n = blockIdx.x * 256 + threadIdx.x;
    if (n >= NN) return;
    int s49 = n >> DSUP_BITS;
    int l = n & (DSUP - 1);
    float sum = p[n];                          // self-loop
#pragma unroll
    for (int j = 0; j < NPAIR; ++j)
        sum += acc1p[(size_t)(s49 * NPAIR + j) * DSUP + l];
    float di = dinv[n];
    float s = di * sum;
    float g0 = 0.f, g1 = 0.f;
#pragma unroll
    for (int c = 0; c < HC; ++c) {
        float h = fmaxf(fmaf(s, W1[c], b1[c]), 0.f);
        g0 = fmaf(h, W2[2 * c], g0);
        g1 = fmaf(h, W2[2 * c + 1], g1);
    }
    g[n] = make_float2(di * g0, di * g1);
}

// ---------- pass 8: layer-2 tile aggregation ----------

__global__ __launch_bounds__(256) void k_l2tile(const unsigned* __restrict__ merged,
                                                const unsigned* __restrict__ gbase,
                                                const unsigned* __restrict__ totals,
                                                const float2* __restrict__ g,
                                                float2* __restrict__ acc2p) {
    __shared__ float2 gsl[SSL];    // 32 KB
    __shared__ float2 acc[DSUP];   // 16 KB
    int tid = threadIdx.x, bid = blockIdx.x;
    int s49 = bid / NPAIR, jp = bid % NPAIR;
    for (int i = tid; i < DSUP; i += 256) acc[i] = make_float2(0.f, 0.f);
    for (int half = 0; half < 2; ++half) {
        int sl = jp * 2 + half;
        if (sl >= NSL) break;
        __syncthreads();
        int base = sl << SSL_BITS;
        for (int i = tid; i < SSL; i += 256)
            gsl[i] = (base + i < NN) ? g[base + i] : make_float2(0.f, 0.f);
        __syncthreads();
        int k = s49 * NSL + sl;
        unsigned T = totals[k];
        const unsigned* m = merged + gbase[k];
        for (unsigned j = tid * 4; j < T; j += 1024) {
            uv4 e = *(const uv4*)(m + j);
            if (j + 0 < T) { float2 v = gsl[e.x >> DSUP_BITS]; unsigned l = e.x & (DSUP - 1);
                             atomicAdd(&acc[l].x, v.x); atomicAdd(&acc[l].y, v.y); }
            if (j + 1 < T) { float2 v = gsl[e.y >> DSUP_BITS]; unsigned l = e.y & (DSUP - 1);
                             atomicAdd(&acc[l].x, v.x); atomicAdd(&acc[l].y, v.y); }
            if (j + 2 < T) { float2 v = gsl[e.z >> DSUP_BITS]; unsigned l = e.z & (DSUP - 1);
                             atomicAdd(&acc[l].x, v.x); atomicAdd(&acc[l].y, v.y); }
            if (j + 3 < T) { float2 v = gsl[e.w >> DSUP_BITS]; unsigned l = e.w & (DSUP - 1);
                             atomicAdd(&acc[l].x, v.x); atomicAdd(&acc[l].y, v.y); }
        }
    }
    __syncthreads();
    float2* ap = acc2p + (size_t)bid * DSUP;
    for (int i = tid; i < DSUP; i += 256) ap[i] = acc[i];
}

// ---------- pass 9: combine layer-2 partials + epilogue -> out ----------

__global__ __launch_bounds__(256) void k_out(const float2* __restrict__ acc2p,
                                             const float* __restrict__ dinv,
                                             const float2* __restrict__ g,
                                             const float* __restrict__ b2,
                                             float2* __restrict__ out) {
    int n = blockIdx.x * 256 + threadIdx.x;
    if (n >= NN) return;
    int s49 = n >> DSUP_BITS;
    int l = n & (DSUP - 1);
    float2 me = g[n];                          // self-loop
    float a0 = me.x, a1 = me.y;
#pragma unroll
    for (int j = 0; j < NPAIR; ++j) {
        float2 v = acc2p[(size_t)(s49 * NPAIR + j) * DSUP + l];
        a0 += v.x; a1 += v.y;
    }
    float di = dinv[n];
    out[n] = make_float2(fmaf(di, a0, b2[0]), fmaf(di, a1, b2[1]));
}

// ---------- fallback: round-1 atomic-scatter path (small ws) ----------

__global__ __launch_bounds__(256) void f_deg(const int* __restrict__ dst,
                                             unsigned int* __restrict__ deg, int E) {
    int i = blockIdx.x * blockDim.x + threadIdx.x;
    if (i < E) atomicAdd(&deg[dst[i]], 1u);
}
__global__ __launch_bounds__(256) void f_node1(const float* __restrict__ x,
                                               const unsigned int* __restrict__ deg,
                                               float* __restrict__ dinv, float* __restrict__ p,
                                               float* __restrict__ t, int N) {
    int i = blockIdx.x * blockDim.x + threadIdx.x;
    if (i < N) {
        float di = rsqrtf((float)(deg[i] + 1u));
        dinv[i] = di; float pi = di * x[i]; p[i] = pi; t[i] = pi;
    }
}
__global__ __launch_bounds__(256) void f_scatter1(const int* __restrict__ src,
                                                  const int* __restrict__ dst,
                                                  const float* __restrict__ p,
                                                  float* __restrict__ t, int E) {
    int i = blockIdx.x * blockDim.x + threadIdx.x;
    if (i < E) atomicAdd(&t[dst[i]], p[src[i]]);
}
__global__ __launch_bounds__(256) void f_node2(const float* __restrict__ dinv,
                                               const float* __restrict__ t,
                                               const float* __restrict__ W1,
                                               const float* __restrict__ b1,
                                               const float* __restrict__ W2,
                                               float2* __restrict__ g,
                                               float2* __restrict__ acc, int N) {
    int i = blockIdx.x * blockDim.x + threadIdx.x;
    if (i < N) {
        float di = dinv[i]; float s = di * t[i];
        float g0 = 0.f, g1 = 0.f;
#pragma unroll
        for (int c = 0; c < HC; ++c) {
            float h = fmaxf(fmaf(s, W1[c], b1[c]), 0.f);
            g0 = fmaf(h, W2[2 * c], g0); g1 = fmaf(h, W2[2 * c + 1], g1);
        }
        float2 gv = make_float2(di * g0, di * g1);
        g[i] = gv; acc[i] = gv;
    }
}
__global__ __launch_bounds__(256) void f_scatter2(const int* __restrict__ src,
                                                  const int* __restrict__ dst,
                                                  const float2* __restrict__ g,
                                                  float* __restrict__ acc, int E) {
    int i = blockIdx.x * blockDim.x + threadIdx.x;
    if (i < E) {
        int s = src[i], d = dst[i];
        float2 gv = g[s];
        atomicAdd(&acc[2 * d], gv.x);
        atomicAdd(&acc[2 * d + 1], gv.y);
    }
}
__global__ __launch_bounds__(256) void f_out(const float* __restrict__ dinv,
                                             const float* __restrict__ b2,
                                             float* __restrict__ out, int N) {
    int i = blockIdx.x * blockDim.x + threadIdx.x;
    if (i < N) {
        float di = dinv[i];
        out[2 * i]     = fmaf(di, out[2 * i],     b2[0]);
        out[2 * i + 1] = fmaf(di, out[2 * i + 1], b2[1]);
    }
}

extern "C" void kernel_launch(void* const* d_in, const int* in_sizes, int n_in,
                              void* d_out, int out_size, void* d_ws, size_t ws_size,
                              hipStream_t stream) {
    const float* x  = (const float*)d_in[0];
    const int* ei   = (const int*)d_in[1];
    const int* src  = ei;
    const int* dst  = ei + NE;
    const float* W1 = (const float*)d_in[2];
    const float* b1 = (const float*)d_in[3];
    const float* W2 = (const float*)d_in[4];
    const float* b2 = (const float*)d_in[5];

    const int BT = 256;
    const int gridE = (NE + BT - 1) / BT;
    const int gridN = (NN + BT - 1) / BT;

    size_t need = 0;
    auto carve = [&](size_t bytes) { size_t o = need; need += (bytes + 255) & ~(size_t)255; return o; };
    // region A: Hoff + TH + cntpart (consecutive); acc1p (5.2 MB) overlays it after node1
    size_t o_Hoff = carve((size_t)NCH * NT1 * 2);             // 1.92 MB
    size_t o_TH   = carve((size_t)NT1 * NCCP * 2);            // 1.92 MB
    size_t o_cnt  = carve((size_t)NT * DSUP * 2);             // 5.02 MB
    size_t o_tot  = carve((size_t)NT * 4);
    size_t o_gb   = carve((size_t)(NT + 1) * 4);
    size_t o_dinv = carve((size_t)NN * 4);
    size_t o_p    = carve((size_t)NN * 4);
    size_t o_g    = carve((size_t)NN * 8);
    size_t o_bin  = carve((size_t)NCH * CHUNK_S * 4);         // 12.8 MB; acc2p overlays
    size_t o_mrg  = carve((size_t)(NE + 16 * NT + 256) * 4);  // 12.9 MB
    size_t o_acc1 = o_Hoff;                                   // overlay (5.2 <= 8.87 MB)
    size_t o_acc2 = o_bin;                                    // overlay (10.4 <= 12.8 MB)

    if (ws_size >= need) {
        char* ws = (char*)d_ws;
        unsigned short* Hoff = (unsigned short*)(ws + o_Hoff);
        unsigned short* TH   = (unsigned short*)(ws + o_TH);
        unsigned short* cntpart = (unsigned short*)(ws + o_cnt);
        unsigned* totals = (unsigned*)(ws + o_tot);
        unsigned* gbase  = (unsigned*)(ws + o_gb);
        float*    dinv   = (float*)(ws + o_dinv);
        float*    p      = (float*)(ws + o_p);
        float2*   g      = (float2*)(ws + o_g);
        unsigned* binned = (unsigned*)(ws + o_bin);
        unsigned* merged = (unsigned*)(ws + o_mrg);
        float*    acc1p  = (float*)(ws + o_acc1);
        float2*   acc2p  = (float2*)(ws + o_acc2);

        k_sortchunk<<<NCH, 256, 0, stream>>>(src, dst, Hoff, binned);
        k_transT   <<<dim3(25, 39), 256, 0, stream>>>(Hoff, TH);
        k_totals   <<<NT, 64, 0, stream>>>(TH, totals);
        k_base3    <<<1, 1024, 0, stream>>>(totals, gbase);
        k_merge    <<<NT, 256, 0, stream>>>(binned, TH, gbase, merged, cntpart);
        k_node1    <<<gridN, 256, 0, stream>>>(cntpart, x, dinv, p);
        k_l1tile   <<<NBLK1, 256, 0, stream>>>(merged, gbase, totals, p, acc1p);
        k_node2    <<<gridN, 256, 0, stream>>>(acc1p, dinv, p, W1, b1, W2, g);
        k_l2tile   <<<NBLK1, 256, 0, stream>>>(merged, gbase, totals, g, acc2p);
        k_out      <<<gridN, 256, 0, stream>>>(acc2p, dinv, g, b2, (float2*)d_out);
    } else {
        float* out = (float*)d_out;
        char* ws = (char*)d_ws;
        unsigned int* deg = (unsigned int*)ws;
        float* dinv = (float*)(ws + 1 * sizeof(float) * NN);
        float* p    = (float*)(ws + 2 * sizeof(float) * NN);
        float* t    = (float*)(ws + 3 * sizeof(float) * NN);
        float2* g   = (float2*)(ws + 4 * sizeof(float) * NN);

        hipMemsetAsync(deg, 0, NN * sizeof(unsigned int), stream);
        f_deg<<<gridE, BT, 0, stream>>>(dst, deg, NE);
        f_node1<<<gridN, BT, 0, stream>>>(x, deg, dinv, p, t, NN);
        f_scatter1<<<gridE, BT, 0, stream>>>(src, dst, p, t, NE);
        f_node2<<<gridN, BT, 0, stream>>>(dinv, t, W1, b1, W2, g, (float2*)out, NN);
        f_scatter2<<<gridE, BT, 0, stream>>>(src, dst, g, out, NE);
        f_out<<<gridN, BT, 0, stream>>>(dinv, b2, out, NN);
    }
}

// Round 11
// 159.703 us; speedup vs baseline: 1.3511x; 1.3511x over previous
//
#include <hip/hip_runtime.h>

#define NN 100000
#define NE 3200000
#define HC 16

#define BKT_BITS 7
#define BKT_NODES 128                 // nodes per bucket
#define NB 782                        // ceil(NN / 128) buckets
#define NB1 783                       // NB + sentinel column
#define CHUNK_S 4096                  // edges per sort block
#define NCC2 782                      // ceil(NE / CHUNK_S)
#define NCCP 784                      // padded TH row stride (u16)
#define MCAP 5120                     // stage capacity (bucket max ~4320)
#define EPAD ((unsigned)NN << BKT_BITS)

typedef unsigned uv4 __attribute__((ext_vector_type(4)));
typedef int      iv4 __attribute__((ext_vector_type(4)));

// ---------- pass 1: per-chunk counting sort by dst-bucket ----------

__global__ __launch_bounds__(256) void k_sortchunk(const int* __restrict__ src,
                                                   const int* __restrict__ dst,
                                                   unsigned short* __restrict__ Hoff,
                                                   unsigned* __restrict__ binned) {
    __shared__ unsigned h[NB1];
    __shared__ unsigned sorted[CHUNK_S];
    __shared__ unsigned wsum[4];
    int tid = threadIdx.x;
    int c = blockIdx.x;
    int b0 = c * CHUNK_S;
    int e1 = min(b0 + CHUNK_S, NE);
    int cnt = e1 - b0;

    for (int j = tid; j < NB1; j += 256) h[j] = 0;
    __syncthreads();

    for (int v = b0 + tid * 4; v + 3 < e1; v += 1024) {
        iv4 d4 = *(const iv4*)(dst + v);
        atomicAdd(&h[((unsigned)d4.x) >> BKT_BITS], 1u);
        atomicAdd(&h[((unsigned)d4.y) >> BKT_BITS], 1u);
        atomicAdd(&h[((unsigned)d4.z) >> BKT_BITS], 1u);
        atomicAdd(&h[((unsigned)d4.w) >> BKT_BITS], 1u);
    }
    __syncthreads();

    int i0 = tid * 4;
    unsigned v0 = (i0 + 0 < NB1) ? h[i0 + 0] : 0;
    unsigned v1 = (i0 + 1 < NB1) ? h[i0 + 1] : 0;
    unsigned v2 = (i0 + 2 < NB1) ? h[i0 + 2] : 0;
    unsigned v3 = (i0 + 3 < NB1) ? h[i0 + 3] : 0;
    unsigned lsum = v0 + v1 + v2 + v3;
    unsigned sc = lsum;
#pragma unroll
    for (int off = 1; off < 64; off <<= 1) {
        unsigned u = __shfl_up(sc, off, 64);
        if ((tid & 63) >= off) sc += u;
    }
    int wave = tid >> 6;
    if ((tid & 63) == 63) wsum[wave] = sc;
    __syncthreads();
    unsigned wpre = 0;
    for (int w = 0; w < wave; ++w) wpre += wsum[w];
    unsigned excl = wpre + sc - lsum;
    __syncthreads();
    if (i0 + 0 < NB1) h[i0 + 0] = excl;
    if (i0 + 1 < NB1) h[i0 + 1] = excl + v0;
    if (i0 + 2 < NB1) h[i0 + 2] = excl + v0 + v1;
    if (i0 + 3 < NB1) h[i0 + 3] = excl + v0 + v1 + v2;

    unsigned short* row = Hoff + (size_t)c * NB1;
    if (i0 + 0 < NB1) row[i0 + 0] = (unsigned short)excl;
    if (i0 + 1 < NB1) row[i0 + 1] = (unsigned short)(excl + v0);
    if (i0 + 2 < NB1) row[i0 + 2] = (unsigned short)(excl + v0 + v1);
    if (i0 + 3 < NB1) row[i0 + 3] = (unsigned short)(excl + v0 + v1 + v2);
    __syncthreads();

    for (int v = b0 + tid * 4; v + 3 < e1; v += 1024) {
        iv4 d4 = *(const iv4*)(dst + v);
        iv4 s4 = *(const iv4*)(src + v);
        {   unsigned d = (unsigned)d4.x, s = (unsigned)s4.x;
            unsigned pos = atomicAdd(&h[d >> BKT_BITS], 1u);
            sorted[pos] = (s << BKT_BITS) | (d & (BKT_NODES - 1)); }
        {   unsigned d = (unsigned)d4.y, s = (unsigned)s4.y;
            unsigned pos = atomicAdd(&h[d >> BKT_BITS], 1u);
            sorted[pos] = (s << BKT_BITS) | (d & (BKT_NODES - 1)); }
        {   unsigned d = (unsigned)d4.z, s = (unsigned)s4.z;
            unsigned pos = atomicAdd(&h[d >> BKT_BITS], 1u);
            sorted[pos] = (s << BKT_BITS) | (d & (BKT_NODES - 1)); }
        {   unsigned d = (unsigned)d4.w, s = (unsigned)s4.w;
            unsigned pos = atomicAdd(&h[d >> BKT_BITS], 1u);
            sorted[pos] = (s << BKT_BITS) | (d & (BKT_NODES - 1)); }
    }
    __syncthreads();

    unsigned* out = binned + (size_t)c * CHUNK_S;
    for (int j = tid * 4; j + 3 < cnt; j += 1024)
        *(uv4*)(out + j) = *(const uv4*)(sorted + j);
}

// ---------- pass 2: transpose Hoff[chunk][bucket] -> TH[bucket][chunk] ----------

__global__ __launch_bounds__(256) void k_transT(const unsigned short* __restrict__ Hoff,
                                                unsigned short* __restrict__ TH) {
    __shared__ unsigned short tile[32][33];
    int tx = threadIdx.x & 31;
    int ty0 = (threadIdx.x >> 5) * 4;
    int c0 = blockIdx.x * 32;
    int b0 = blockIdx.y * 32;
#pragma unroll
    for (int k = 0; k < 4; ++k) {
        int c = c0 + ty0 + k, b = b0 + tx;
        tile[ty0 + k][tx] = (c < NCC2 && b < NB1) ? Hoff[(size_t)c * NB1 + b] : (unsigned short)0;
    }
    __syncthreads();
#pragma unroll
    for (int k = 0; k < 4; ++k) {
        int b = b0 + ty0 + k, c = c0 + tx;
        if (b < NB1 && c < NCC2) TH[(size_t)b * NCCP + c] = tile[tx][ty0 + k];
    }
}

// ---------- pass 3: per-bucket totals + global base scan ----------

__global__ __launch_bounds__(64) void k_totals(const unsigned short* __restrict__ TH,
                                               unsigned* __restrict__ totals) {
    int b = blockIdx.x;
    int lane = threadIdx.x;
    const unsigned short* r0 = TH + (size_t)b * NCCP;
    const unsigned short* r1 = r0 + NCCP;
    unsigned s = 0;
    for (int c = lane; c < NCC2; c += 64) s += (unsigned)r1[c] - (unsigned)r0[c];
#pragma unroll
    for (int off = 32; off >= 1; off >>= 1) s += __shfl_xor(s, off, 64);
    if (lane == 0) totals[b] = s;
}

__global__ __launch_bounds__(1024) void k_base2(const unsigned* __restrict__ totals,
                                                unsigned* __restrict__ gbase) {
    __shared__ unsigned s[1024];
    int t = threadIdx.x;
    unsigned v = (t < NB) ? ((totals[t] + 15u) & ~15u) : 0;
    s[t] = v;
    __syncthreads();
    for (int off = 1; off < 1024; off <<= 1) {
        unsigned u = (t >= off) ? s[t - off] : 0;
        __syncthreads();
        s[t] += u;
        __syncthreads();
    }
    if (t < NB) gbase[t] = s[t] - v;
}

// ---------- pass 4: merge segments -> contiguous runs + per-bucket CSR offsets,
//                    fused degree/dinv/p ----------

__global__ __launch_bounds__(256) void k_merge_deg(const unsigned* __restrict__ binned,
                                                   const unsigned short* __restrict__ TH,
                                                   const unsigned* __restrict__ gbase,
                                                   const float* __restrict__ x,
                                                   unsigned* __restrict__ merged,
                                                   unsigned short* __restrict__ cofsg,
                                                   float* __restrict__ dinv,
                                                   float* __restrict__ p) {
    __shared__ unsigned short th0s[NCC2];
    __shared__ unsigned short lens[NCC2];
    __shared__ unsigned S[NB1];
    __shared__ unsigned wsum[4];
    __shared__ unsigned cnt[BKT_NODES];
    __shared__ unsigned stage[MCAP];
    __shared__ unsigned short cof[BKT_NODES + 2];
    __shared__ unsigned wsA;
    int tid = threadIdx.x, b = blockIdx.x;

    const unsigned short* r0 = TH + (size_t)b * NCCP;
    const unsigned short* r1 = r0 + NCCP;
    for (int c = tid; c < NCC2; c += 256) {
        unsigned a = r0[c];
        th0s[c] = (unsigned short)a;
        lens[c] = (unsigned short)((unsigned)r1[c] - a);
    }
    if (tid < BKT_NODES) cnt[tid] = 0;
    __syncthreads();

    // exclusive scan of lens -> S
    int i0 = tid * 4;
    unsigned v0 = (i0 + 0 < NCC2) ? (unsigned)lens[i0 + 0] : 0;
    unsigned v1 = (i0 + 1 < NCC2) ? (unsigned)lens[i0 + 1] : 0;
    unsigned v2 = (i0 + 2 < NCC2) ? (unsigned)lens[i0 + 2] : 0;
    unsigned v3 = (i0 + 3 < NCC2) ? (unsigned)lens[i0 + 3] : 0;
    unsigned lsum = v0 + v1 + v2 + v3;
    unsigned sc = lsum;
#pragma unroll
    for (int off = 1; off < 64; off <<= 1) {
        unsigned u = __shfl_up(sc, off, 64);
        if ((tid & 63) >= off) sc += u;
    }
    int wave = tid >> 6;
    if ((tid & 63) == 63) wsum[wave] = sc;
    __syncthreads();
    unsigned wpre = 0;
    for (int w = 0; w < wave; ++w) wpre += wsum[w];
    unsigned excl = wpre + sc - lsum;
    if (i0 + 0 <= NCC2) S[i0 + 0] = excl;
    if (i0 + 1 <= NCC2) S[i0 + 1] = excl + v0;
    if (i0 + 2 <= NCC2) S[i0 + 2] = excl + v0 + v1;
    if (i0 + 3 <= NCC2) S[i0 + 3] = excl + v0 + v1 + v2;
    __syncthreads();

    unsigned T = S[NCC2];
    unsigned Tr = (T + 15u) & ~15u;
    unsigned gb = gbase[b];
    if (tid < 16) {
        unsigned q = T + tid;
        if (q < Tr) stage[q] = EPAD;
    }

    // gather segments -> LDS stage (+ dst-local degree count)
    for (int c = tid; c < NCC2; c += 256) {
        unsigned off = th0s[c], L = lens[c], base = S[c];
        const unsigned* seg = binned + (size_t)c * CHUNK_S + off;
        for (unsigned j = 0; j < L; ++j) {
            unsigned e = seg[j];
            atomicAdd(&cnt[e & (BKT_NODES - 1)], 1u);
            stage[base + j] = e;
        }
    }
    __syncthreads();

    // contiguous aligned write-out (gb % 16 == 0)
    for (unsigned j = tid * 4; j < Tr; j += 1024)
        *(uv4*)(merged + gb + j) = *(const uv4*)(stage + j);

    // scan cnt[128] -> cofs (CSR offsets within bucket)
    unsigned cv = (tid < BKT_NODES) ? cnt[tid] : 0u;
    unsigned csc = cv;
#pragma unroll
    for (int off = 1; off < 64; off <<= 1) {
        unsigned u = __shfl_up(csc, off, 64);
        if ((tid & 63) >= off) csc += u;
    }
    if (tid == 63) wsA = csc;
    __syncthreads();
    if (tid < BKT_NODES) {
        unsigned incl = csc + ((tid >= 64) ? wsA : 0u);
        cof[tid + 1] = (unsigned short)incl;
    }
    if (tid == 0) cof[0] = 0;
    __syncthreads();
    if (tid < BKT_NODES + 1)
        cofsg[(size_t)b * (BKT_NODES + 2) + tid] = cof[tid];

    int node = b * BKT_NODES + tid;
    if (tid < BKT_NODES) {
        if (node < NN) {
            float di = rsqrtf((float)(cnt[tid] + 1u));    // +1 self-loop
            dinv[node] = di;
            p[node] = di * x[node];
        } else if (node == NN) {
            p[node] = 0.f;
        }
    }
}

// ---------- pass 5: layer-1 — LDS counting-sort + register accumulation (no float atomics) ----------

__global__ __launch_bounds__(256) void k_agg1(const unsigned* __restrict__ merged,
                                              const unsigned* __restrict__ gbase,
                                              const unsigned* __restrict__ totals,
                                              const unsigned short* __restrict__ cofsg,
                                              const float* __restrict__ dinv,
                                              const float* __restrict__ p,
                                              const float* __restrict__ W1,
                                              const float* __restrict__ b1,
                                              const float* __restrict__ W2,
                                              float2* __restrict__ g) {
    __shared__ unsigned short cof[BKT_NODES + 2];
    __shared__ unsigned cur[BKT_NODES];
    __shared__ unsigned se[MCAP];
    __shared__ float part[256];
    int tid = threadIdx.x, b = blockIdx.x;
    if (tid < BKT_NODES + 1) cof[tid] = cofsg[(size_t)b * (BKT_NODES + 2) + tid];
    __syncthreads();
    if (tid < BKT_NODES) cur[tid] = cof[tid];
    __syncthreads();
    unsigned T = totals[b];
    const unsigned* m = merged + gbase[b];
    for (unsigned j = tid * 4; j < T; j += 1024) {
        uv4 e = *(const uv4*)(m + j);
        if (j + 0 < T) { unsigned w = e.x; se[atomicAdd(&cur[w & (BKT_NODES - 1)], 1u)] = w >> BKT_BITS; }
        if (j + 1 < T) { unsigned w = e.y; se[atomicAdd(&cur[w & (BKT_NODES - 1)], 1u)] = w >> BKT_BITS; }
        if (j + 2 < T) { unsigned w = e.z; se[atomicAdd(&cur[w & (BKT_NODES - 1)], 1u)] = w >> BKT_BITS; }
        if (j + 3 < T) { unsigned w = e.w; se[atomicAdd(&cur[w & (BKT_NODES - 1)], 1u)] = w >> BKT_BITS; }
    }
    __syncthreads();

    int nl = tid >> 1, half = tid & 1;
    unsigned o0 = cof[nl], o1 = cof[nl + 1];
    unsigned len = o1 - o0, mid = o0 + ((len + 1) >> 1);
    unsigned s = half ? mid : o0;
    unsigned e = half ? o1 : mid;
    float sum = 0.f;
    unsigned i = s;
    for (; i + 3 < e; i += 4) {
        unsigned a0 = se[i], a1 = se[i + 1], a2 = se[i + 2], a3 = se[i + 3];
        float x0 = p[a0], x1 = p[a1], x2 = p[a2], x3 = p[a3];
        sum += (x0 + x1) + (x2 + x3);
    }
    for (; i < e; ++i) sum += p[se[i]];
    part[tid] = sum;
    __syncthreads();

    if (!half) {
        int node = b * BKT_NODES + nl;
        if (node < NN) {
            float di = dinv[node];
            float sf = di * (part[tid] + part[tid + 1] + p[node]);   // + self-loop
            float g0 = 0.f, g1 = 0.f;
#pragma unroll
            for (int c = 0; c < HC; ++c) {
                float h = fmaxf(fmaf(sf, W1[c], b1[c]), 0.f);
                g0 = fmaf(h, W2[2 * c], g0);
                g1 = fmaf(h, W2[2 * c + 1], g1);
            }
            g[node] = make_float2(di * g0, di * g1);
        }
    }
}

// ---------- pass 6: layer-2 — same structure, float2 ----------

__global__ __launch_bounds__(256) void k_agg2(const unsigned* __restrict__ merged,
                                              const unsigned* __restrict__ gbase,
                                              const unsigned* __restrict__ totals,
                                              const unsigned short* __restrict__ cofsg,
                                              const float* __restrict__ dinv,
                                              const float2* __restrict__ g,
                                              const float* __restrict__ b2,
                                              float2* __restrict__ out) {
    __shared__ unsigned short cof[BKT_NODES + 2];
    __shared__ unsigned cur[BKT_NODES];
    __shared__ unsigned se[MCAP];
    __shared__ float2 part[256];
    int tid = threadIdx.x, b = blockIdx.x;
    if (tid < BKT_NODES + 1) cof[tid] = cofsg[(size_t)b * (BKT_NODES + 2) + tid];
    __syncthreads();
    if (tid < BKT_NODES) cur[tid] = cof[tid];
    __syncthreads();
    unsigned T = totals[b];
    const unsigned* m = merged + gbase[b];
    for (unsigned j = tid * 4; j < T; j += 1024) {
        uv4 e = *(const uv4*)(m + j);
        if (j + 0 < T) { unsigned w = e.x; se[atomicAdd(&cur[w & (BKT_NODES - 1)], 1u)] = w >> BKT_BITS; }
        if (j + 1 < T) { unsigned w = e.y; se[atomicAdd(&cur[w & (BKT_NODES - 1)], 1u)] = w >> BKT_BITS; }
        if (j + 2 < T) { unsigned w = e.z; se[atomicAdd(&cur[w & (BKT_NODES - 1)], 1u)] = w >> BKT_BITS; }
        if (j + 3 < T) { unsigned w = e.w; se[atomicAdd(&cur[w & (BKT_NODES - 1)], 1u)] = w >> BKT_BITS; }
    }
    __syncthreads();

    int nl = tid >> 1, half = tid & 1;
    unsigned o0 = cof[nl], o1 = cof[nl + 1];
    unsigned len = o1 - o0, mid = o0 + ((len + 1) >> 1);
    unsigned s = half ? mid : o0;
    unsigned e = half ? o1 : mid;
    float sx = 0.f, sy = 0.f;
    unsigned i = s;
    for (; i + 3 < e; i += 4) {
        unsigned a0 = se[i], a1 = se[i + 1], a2 = se[i + 2], a3 = se[i + 3];
        float2 v0 = g[a0], v1 = g[a1], v2 = g[a2], v3 = g[a3];
        sx += (v0.x + v1.x) + (v2.x + v3.x);
        sy += (v0.y + v1.y) + (v2.y + v3.y);
    }
    for (; i < e; ++i) { float2 v = g[se[i]]; sx += v.x; sy += v.y; }
    part[tid] = make_float2(sx, sy);
    __syncthreads();

    if (!half) {
        int node = b * BKT_NODES + nl;
        if (node < NN) {
            float di = dinv[node];
            float2 me = g[node];
            float ax = part[tid].x + part[tid + 1].x + me.x;
            float ay = part[tid].y + part[tid + 1].y + me.y;
            out[node] = make_float2(fmaf(di, ax, b2[0]), fmaf(di, ay, b2[1]));
        }
    }
}

// ---------- fallback: round-1 atomic-scatter path (small ws) ----------

__global__ __launch_bounds__(256) void f_deg(const int* __restrict__ dst,
                                             unsigned int* __restrict__ deg, int E) {
    int i = blockIdx.x * blockDim.x + threadIdx.x;
    if (i < E) atomicAdd(&deg[dst[i]], 1u);
}
__global__ __launch_bounds__(256) void f_node1(const float* __restrict__ x,
                                               const unsigned int* __restrict__ deg,
                                               float* __restrict__ dinv, float* __restrict__ p,
                                               float* __restrict__ t, int N) {
    int i = blockIdx.x * blockDim.x + threadIdx.x;
    if (i < N) {
        float di = rsqrtf((float)(deg[i] + 1u));
        dinv[i] = di; float pi = di * x[i]; p[i] = pi; t[i] = pi;
    }
}
__global__ __launch_bounds__(256) void f_scatter1(const int* __restrict__ src,
                                                  const int* __restrict__ dst,
                                                  const float* __restrict__ p,
                                                  float* __restrict__ t, int E) {
    int i = blockIdx.x * blockDim.x + threadIdx.x;
    if (i < E) atomicAdd(&t[dst[i]], p[src[i]]);
}
__global__ __launch_bounds__(256) void f_node2(const float* __restrict__ dinv,
                                               const float* __restrict__ t,
                                               const float* __restrict__ W1,
                                               const float* __restrict__ b1,
                                               const float* __restrict__ W2,
                                               float2* __restrict__ g,
                                               float2* __restrict__ acc, int N) {
    int i = blockIdx.x * blockDim.x + threadIdx.x;
    if (i < N) {
        float di = dinv[i]; float s = di * t[i];
        float g0 = 0.f, g1 = 0.f;
#pragma unroll
        for (int c = 0; c < HC; ++c) {
            float h = fmaxf(fmaf(s, W1[c], b1[c]), 0.f);
            g0 = fmaf(h, W2[2 * c], g0); g1 = fmaf(h, W2[2 * c + 1], g1);
        }
        float2 gv = make_float2(di * g0, di * g1);
        g[i] = gv; acc[i] = gv;
    }
}
__global__ __launch_bounds__(256) void f_scatter2(const int* __restrict__ src,
                                                  const int* __restrict__ dst,
                                                  const float2* __restrict__ g,
                                                  float* __restrict__ acc, int E) {
    int i = blockIdx.x * blockDim.x + threadIdx.x;
    if (i < E) {
        int s = src[i], d = dst[i];
        float2 gv = g[s];
        atomicAdd(&acc[2 * d], gv.x);
        atomicAdd(&acc[2 * d + 1], gv.y);
    }
}
__global__ __launch_bounds__(256) void f_out(const float* __restrict__ dinv,
                                             const float* __restrict__ b2,
                                             float* __restrict__ out, int N) {
    int i = blockIdx.x * blockDim.x + threadIdx.x;
    if (i < N) {
        float di = dinv[i];
        out[2 * i]     = fmaf(di, out[2 * i],     b2[0]);
        out[2 * i + 1] = fmaf(di, out[2 * i + 1], b2[1]);
    }
}

extern "C" void kernel_launch(void* const* d_in, const int* in_sizes, int n_in,
                              void* d_out, int out_size, void* d_ws, size_t ws_size,
                              hipStream_t stream) {
    const float* x  = (const float*)d_in[0];
    const int* ei   = (const int*)d_in[1];
    const int* src  = ei;
    const int* dst  = ei + NE;
    const float* W1 = (const float*)d_in[2];
    const float* b1 = (const float*)d_in[3];
    const float* W2 = (const float*)d_in[4];
    const float* b2 = (const float*)d_in[5];

    const int BT = 256;
    const int gridE = (NE + BT - 1) / BT;
    const int gridN = (NN + BT - 1) / BT;

    size_t need = 0;
    auto carve = [&](size_t bytes) { size_t o = need; need += (bytes + 255) & ~(size_t)255; return o; };
    size_t o_Hoff = carve((size_t)NCC2 * NB1 * 2);
    size_t o_TH   = carve((size_t)NB1 * NCCP * 2);
    size_t o_tot  = carve((size_t)NB * 4);
    size_t o_gb   = carve((size_t)(NB + 1) * 4);
    size_t o_cofs = carve((size_t)NB * (BKT_NODES + 2) * 2);
    size_t o_dinv = carve((size_t)NN * 4);
    size_t o_p    = carve((size_t)(NN + 1) * 4);
    size_t o_g    = carve((size_t)(NN + 1) * 8);
    size_t o_bin  = carve((size_t)NCC2 * CHUNK_S * 4);
    size_t o_mrg  = carve((size_t)(NE + 16 * NB + 64) * 4);

    if (ws_size >= need) {
        char* ws = (char*)d_ws;
        unsigned short* Hoff = (unsigned short*)(ws + o_Hoff);
        unsigned short* TH   = (unsigned short*)(ws + o_TH);
        unsigned* totals = (unsigned*)(ws + o_tot);
        unsigned* gbase  = (unsigned*)(ws + o_gb);
        unsigned short* cofs = (unsigned short*)(ws + o_cofs);
        float*    dinv   = (float*)(ws + o_dinv);
        float*    p      = (float*)(ws + o_p);
        float2*   g      = (float2*)(ws + o_g);
        unsigned* binned = (unsigned*)(ws + o_bin);
        unsigned* merged = (unsigned*)(ws + o_mrg);

        k_sortchunk<<<NCC2, 256, 0, stream>>>(src, dst, Hoff, binned);
        k_transT   <<<dim3(25, 25), 256, 0, stream>>>(Hoff, TH);
        k_totals   <<<NB, 64, 0, stream>>>(TH, totals);
        k_base2    <<<1, 1024, 0, stream>>>(totals, gbase);
        k_merge_deg<<<NB, 256, 0, stream>>>(binned, TH, gbase, x, merged, cofs, dinv, p);
        k_agg1     <<<NB, 256, 0, stream>>>(merged, gbase, totals, cofs, dinv, p, W1, b1, W2, g);
        k_agg2     <<<NB, 256, 0, stream>>>(merged, gbase, totals, cofs, dinv, g, b2, (float2*)d_out);
    } else {
        float* out = (float*)d_out;
        char* ws = (char*)d_ws;
        unsigned int* deg = (unsigned int*)ws;
        float* dinv = (float*)(ws + 1 * sizeof(float) * NN);
        float* p    = (float*)(ws + 2 * sizeof(float) * NN);
        float* t    = (float*)(ws + 3 * sizeof(float) * NN);
        float2* g   = (float2*)(ws + 4 * sizeof(float) * NN);

        hipMemsetAsync(deg, 0, NN * sizeof(unsigned int), stream);
        f_deg<<<gridE, BT, 0, stream>>>(dst, deg, NE);
        f_node1<<<gridN, BT, 0, stream>>>(x, deg, dinv, p, t, NN);
        f_scatter1<<<gridE, BT, 0, stream>>>(src, dst, p, t, NE);
        f_node2<<<gridN, BT, 0, stream>>>(dinv, t, W1, b1, W2, g, (float2*)out, NN);
        f_scatter2<<<gridE, BT, 0, stream>>>(src, dst, g, out, NE);
        f_out<<<gridN, BT, 0, stream>>>(dinv, b2, out, NN);
    }
}